// Round 1
// baseline (2568.836 us; speedup 1.0000x reference)
//
#include <hip/hip_runtime.h>
#include <math.h>

// GRUModel: B=64,S=288,Fc=16,Fo=32,D=256,QKV=64,HEADS=4,hd=16
// Round 1: all-fp32 correctness-first implementation.
// ws layout (floats): X[18432*256] | Y[18432*256] | G[18432*512] | C[18432*256]
//   = 23,592,960 floats = 94.4 MB total.

#define EPS 1e-5f
constexpr int B_ = 64, S_ = 288, FC = 16, FO = 32, D_ = 256, QKVN = 64, HD = 16;
constexpr int TOK = B_ * S_;            // 18432
constexpr int NX = TOK * D_;            // 4718592
constexpr int NG = TOK * 512;           // 9437184

// block-wide sum; blockDim multiple of 64, <=512. sc: >= blockDim/64 floats.
__device__ __forceinline__ float blk_sum(float v, float* sc) {
  #pragma unroll
  for (int o = 32; o > 0; o >>= 1) v += __shfl_down(v, o, 64);
  int tid = threadIdx.x;
  int wid = tid >> 6, nw = blockDim.x >> 6;
  __syncthreads();                      // protect sc from previous use
  if ((tid & 63) == 0) sc[wid] = v;
  __syncthreads();
  float s = 0.f;
  for (int w = 0; w < nw; ++w) s += sc[w];
  return s;
}

// ---------------- input projection + LN0: one block per token, 256 thr -------
__global__ __launch_bounds__(256) void inproj_ln(
    const float* __restrict__ xc, const float* __restrict__ Wi,
    const float* __restrict__ bi, const float* __restrict__ sc_,
    const float* __restrict__ bb, float* __restrict__ X) {
  __shared__ float sc[8];
  int tok = blockIdx.x, j = threadIdx.x;
  const float* xr = xc + tok * FC;
  float acc = bi[j];
  #pragma unroll
  for (int i = 0; i < FC; ++i) acc += xr[i] * Wi[i * D_ + j];
  float m = blk_sum(acc, sc) * (1.f / D_);
  float d = acc - m;
  float var = blk_sum(d * d, sc) * (1.f / D_);
  X[tok * D_ + j] = d * rsqrtf(var + EPS) * sc_[j] + bb[j];
}

// ---------------- LN over D=256 per token, optional residual add -------------
template <int RES>
__global__ __launch_bounds__(256) void ln_token(
    const float* __restrict__ in, const float* __restrict__ sc_,
    const float* __restrict__ bb, const float* __restrict__ resid,
    float* __restrict__ out) {
  __shared__ float sc[8];
  int tok = blockIdx.x, j = threadIdx.x;
  float v = in[tok * D_ + j];
  float m = blk_sum(v, sc) * (1.f / D_);
  float d = v - m;
  float var = blk_sum(d * d, sc) * (1.f / D_);
  float r = d * rsqrtf(var + EPS) * sc_[j] + bb[j];
  if (RES) r += resid[tok * D_ + j];
  out[tok * D_ + j] = r;
}

// ---------------- generic fp32 GEMM: OUT[M,N] = act(A[M,K]@W[K,N]+b)(+resid) -
// TM=32 rows/block, 256 threads. NC = cols handled per block (256 or 64).
// grid = (M/32, N/NC). K runtime (256 or 64), divisible by 4.
template <int ACT, int NC, int RES>
__global__ __launch_bounds__(256) void gemm_bias(
    const float* __restrict__ A, const float* __restrict__ W,
    const float* __restrict__ bias, const float* __restrict__ resid,
    float* __restrict__ OUT, int K, int N) {
  constexpr int TM = 32;
  constexpr int NT = TM * NC / 256;     // rows per thread
  __shared__ float4 As4[TM * 64];       // up to 32x256 fp32 = 32KB
  int row0 = blockIdx.x * TM;
  int tid = threadIdx.x;
  const float4* Ag = (const float4*)(A + (size_t)row0 * K);
  int n4 = TM * K / 4;
  for (int i = tid; i < n4; i += 256) As4[i] = Ag[i];
  __syncthreads();
  int col = blockIdx.y * NC + (tid % NC);
  int rg = tid / NC;
  int t0 = rg * NT;
  float bv = bias[col];
  float acc[NT];
  #pragma unroll
  for (int t = 0; t < NT; ++t) acc[t] = bv;
  int K4 = K >> 2;
  for (int k0 = 0; k0 < K4; ++k0) {
    float w0 = W[(k0 * 4 + 0) * N + col];
    float w1 = W[(k0 * 4 + 1) * N + col];
    float w2 = W[(k0 * 4 + 2) * N + col];
    float w3 = W[(k0 * 4 + 3) * N + col];
    #pragma unroll
    for (int t = 0; t < NT; ++t) {
      float4 a = As4[(t0 + t) * K4 + k0];
      acc[t] += a.x * w0 + a.y * w1 + a.z * w2 + a.w * w3;
    }
  }
  #pragma unroll
  for (int t = 0; t < NT; ++t) {
    int row = row0 + t0 + t;
    float v = acc[t];
    if (ACT == 1) v = 1.f / (1.f + __expf(-v));
    if (RES) v += resid[(size_t)row * N + col];
    OUT[(size_t)row * N + col] = v;
  }
}

// ---------------- GRU sequential scan: one block per batch, 256 thr ----------
// gates G[b,t,0:256]=r, [256:512]=u (pre-sigmoided); C = x@Wcx+bcx.
// h_j in register of thread j. v = r*h broadcast via LDS. Wch streamed from L2:
// wave-group g covers k-rows [64g,64g+64), thread col-quad 4c..4c+3, LDS reduce.
__global__ __launch_bounds__(256) void gru_scan(
    const float* __restrict__ G, const float* __restrict__ C,
    const float* __restrict__ Wch, const float* __restrict__ bch,
    float* __restrict__ Y) {
  __shared__ float lv[D_];
  __shared__ float lp[4 * 260];
  int b = blockIdx.x, tid = threadIdx.x;
  int c = tid & 63, g = tid >> 6;
  float h = 0.f;
  float bchv = bch[tid];
  const float* W0 = Wch + (g * 64) * D_ + 4 * c;
  for (int t = 0; t < S_; ++t) {
    size_t base = (size_t)(b * S_ + t);
    float r = G[base * 512 + tid];
    lv[tid] = r * h;
    __syncthreads();
    float4 a = {0.f, 0.f, 0.f, 0.f};
    const float* Wp = W0;
    #pragma unroll 4
    for (int i4 = 0; i4 < 16; ++i4) {
      float4 v4 = *(const float4*)&lv[(g << 6) + i4 * 4];
      float4 w0 = *(const float4*)(Wp);
      float4 w1 = *(const float4*)(Wp + D_);
      float4 w2 = *(const float4*)(Wp + 2 * D_);
      float4 w3 = *(const float4*)(Wp + 3 * D_);
      a.x += v4.x * w0.x + v4.y * w1.x + v4.z * w2.x + v4.w * w3.x;
      a.y += v4.x * w0.y + v4.y * w1.y + v4.z * w2.y + v4.w * w3.y;
      a.z += v4.x * w0.z + v4.y * w1.z + v4.z * w2.z + v4.w * w3.z;
      a.w += v4.x * w0.w + v4.y * w1.w + v4.z * w2.w + v4.w * w3.w;
      Wp += 4 * D_;
    }
    *(float4*)&lp[g * 260 + 4 * c] = a;
    __syncthreads();
    float sum = C[base * D_ + tid] + bchv + lp[0 * 260 + tid] +
                lp[1 * 260 + tid] + lp[2 * 260 + tid] + lp[3 * 260 + tid];
    float cand = tanhf(sum);
    float u = G[base * 512 + 256 + tid];
    h = u * h + (1.f - u) * cand;
    Y[base * D_ + tid] = h;
    // next lv write only happens after next-iteration's first sync is safe:
    // at 2nd sync all lv reads of this step are done.
  }
}

// ---------------- flash attention: block=(b,head), 320 thr, K/V in LDS -------
__global__ __launch_bounds__(320) void attn(
    const float* __restrict__ Q, const float* __restrict__ Kv,
    const float* __restrict__ V, float* __restrict__ AO) {
  __shared__ float Kl[S_ * HD];
  __shared__ float Vl[S_ * HD];
  int b = blockIdx.x, hh = blockIdx.y;
  int tid = threadIdx.x;
  int hoff = hh * HD;
  for (int idx = tid; idx < S_ * HD; idx += 320) {
    int row = idx >> 4, d = idx & 15;
    Kl[idx] = Kv[((size_t)(b * S_ + row)) * QKVN + hoff + d];
    Vl[idx] = V[((size_t)(b * S_ + row)) * QKVN + hoff + d];
  }
  __syncthreads();
  if (tid >= S_) return;
  const float* qp = Q + ((size_t)(b * S_ + tid)) * QKVN + hoff;
  float4 q0 = *(const float4*)(qp + 0);
  float4 q1 = *(const float4*)(qp + 4);
  float4 q2 = *(const float4*)(qp + 8);
  float4 q3 = *(const float4*)(qp + 12);
  float m = -1e30f, l = 0.f;
  float4 o0 = {0, 0, 0, 0}, o1 = {0, 0, 0, 0}, o2 = {0, 0, 0, 0},
         o3 = {0, 0, 0, 0};
  for (int k = 0; k < S_; ++k) {
    const float4* kp = (const float4*)&Kl[k * HD];
    float4 k0 = kp[0], k1 = kp[1], k2 = kp[2], k3 = kp[3];
    float s = q0.x * k0.x + q0.y * k0.y + q0.z * k0.z + q0.w * k0.w +
              q1.x * k1.x + q1.y * k1.y + q1.z * k1.z + q1.w * k1.w +
              q2.x * k2.x + q2.y * k2.y + q2.z * k2.z + q2.w * k2.w +
              q3.x * k3.x + q3.y * k3.y + q3.z * k3.z + q3.w * k3.w;
    s *= 0.25f;                          // 1/sqrt(16)
    float mn = fmaxf(m, s);
    float corr = __expf(m - mn);
    float p = __expf(s - mn);
    l = l * corr + p;
    const float4* vp = (const float4*)&Vl[k * HD];
    float4 v0 = vp[0], v1 = vp[1], v2 = vp[2], v3 = vp[3];
    o0.x = o0.x * corr + p * v0.x; o0.y = o0.y * corr + p * v0.y;
    o0.z = o0.z * corr + p * v0.z; o0.w = o0.w * corr + p * v0.w;
    o1.x = o1.x * corr + p * v1.x; o1.y = o1.y * corr + p * v1.y;
    o1.z = o1.z * corr + p * v1.z; o1.w = o1.w * corr + p * v1.w;
    o2.x = o2.x * corr + p * v2.x; o2.y = o2.y * corr + p * v2.y;
    o2.z = o2.z * corr + p * v2.z; o2.w = o2.w * corr + p * v2.w;
    o3.x = o3.x * corr + p * v3.x; o3.y = o3.y * corr + p * v3.y;
    o3.z = o3.z * corr + p * v3.z; o3.w = o3.w * corr + p * v3.w;
    m = mn;
  }
  float inv = 1.f / l;
  float* op = AO + ((size_t)(b * S_ + tid)) * QKVN + hoff;
  float4 r0 = {o0.x * inv, o0.y * inv, o0.z * inv, o0.w * inv};
  float4 r1 = {o1.x * inv, o1.y * inv, o1.z * inv, o1.w * inv};
  float4 r2 = {o2.x * inv, o2.y * inv, o2.z * inv, o2.w * inv};
  float4 r3 = {o3.x * inv, o3.y * inv, o3.z * inv, o3.w * inv};
  ((float4*)op)[0] = r0; ((float4*)op)[1] = r1;
  ((float4*)op)[2] = r2; ((float4*)op)[3] = r3;
}

// ---------------- head: pool + concat + d1(LN) + d2(LN) + out ----------------
__global__ __launch_bounds__(128) void head(
    const float* __restrict__ X, const float* __restrict__ xo,
    const float* __restrict__ Wd1, const float* __restrict__ bd1,
    const float* __restrict__ s1, const float* __restrict__ b1,
    const float* __restrict__ Wd2, const float* __restrict__ bd2,
    const float* __restrict__ s2, const float* __restrict__ b2,
    const float* __restrict__ Wout, const float* __restrict__ bout,
    float* __restrict__ out) {
  __shared__ float c[D_ + FO];
  __shared__ float h1[128];
  __shared__ float sc[8];
  int b = blockIdx.x, tid = threadIdx.x;
  for (int cc = tid; cc < D_; cc += 128) {
    float acc = 0.f;
    for (int t = 0; t < S_; ++t) acc += X[((size_t)(b * S_ + t)) * D_ + cc];
    c[cc] = acc * (1.f / S_);
  }
  if (tid < FO) c[D_ + tid] = xo[b * FO + tid];
  __syncthreads();
  // dense1 (128 outputs) + relu + LN
  float v = bd1[tid];
  for (int k = 0; k < D_ + FO; ++k) v += c[k] * Wd1[k * 128 + tid];
  v = fmaxf(v, 0.f);
  float m = blk_sum(v, sc) * (1.f / 128.f);
  float d = v - m;
  float var = blk_sum(d * d, sc) * (1.f / 128.f);
  h1[tid] = d * rsqrtf(var + EPS) * s1[tid] + b1[tid];
  __syncthreads();
  // dense2 (64 outputs) + relu + LN
  float v2 = 0.f;
  if (tid < 64) {
    v2 = bd2[tid];
    for (int k = 0; k < 128; ++k) v2 += h1[k] * Wd2[k * 64 + tid];
    v2 = fmaxf(v2, 0.f);
  }
  float m2 = blk_sum(tid < 64 ? v2 : 0.f, sc) * (1.f / 64.f);
  float d2v = v2 - m2;
  float var2 = blk_sum(tid < 64 ? d2v * d2v : 0.f, sc) * (1.f / 64.f);
  float hv = (tid < 64) ? (d2v * rsqrtf(var2 + EPS) * s2[tid] + b2[tid]) : 0.f;
  float p = (tid < 64) ? hv * Wout[tid] : 0.f;
  float tot = blk_sum(p, sc);
  if (tid == 0) out[b] = tot + bout[0];
}

extern "C" void kernel_launch(void* const* d_in, const int* in_sizes, int n_in,
                              void* d_out, int out_size, void* d_ws,
                              size_t ws_size, hipStream_t stream) {
  const float* x_cgm = (const float*)d_in[0];
  const float* x_other = (const float*)d_in[1];
  const float* W_in = (const float*)d_in[2];
  const float* b_in = (const float*)d_in[3];
  const float* ln0_s = (const float*)d_in[4];
  const float* ln0_b = (const float*)d_in[5];
  const float* g0_Wg = (const float*)d_in[6];
  const float* g0_bg = (const float*)d_in[7];
  const float* g0_Wcx = (const float*)d_in[8];
  const float* g0_bcx = (const float*)d_in[9];
  const float* g0_Wch = (const float*)d_in[10];
  const float* g0_bch = (const float*)d_in[11];
  const float* g1_Wg = (const float*)d_in[12];
  const float* g1_bg = (const float*)d_in[13];
  const float* g1_Wcx = (const float*)d_in[14];
  const float* g1_bcx = (const float*)d_in[15];
  const float* g1_Wch = (const float*)d_in[16];
  const float* g1_bch = (const float*)d_in[17];
  const float* ln1_s = (const float*)d_in[18];
  const float* ln1_b = (const float*)d_in[19];
  const float* ln2_s = (const float*)d_in[20];
  const float* ln2_b = (const float*)d_in[21];
  const float* aln_s = (const float*)d_in[22];
  const float* aln_b = (const float*)d_in[23];
  const float* Wq = (const float*)d_in[24];
  const float* Wk = (const float*)d_in[25];
  const float* Wv = (const float*)d_in[26];
  const float* bq = (const float*)d_in[27];
  const float* bk = (const float*)d_in[28];
  const float* bv = (const float*)d_in[29];
  const float* Wo = (const float*)d_in[30];
  const float* bo = (const float*)d_in[31];
  const float* Wd1 = (const float*)d_in[32];
  const float* bd1 = (const float*)d_in[33];
  const float* lnd1_s = (const float*)d_in[34];
  const float* lnd1_b = (const float*)d_in[35];
  const float* Wd2 = (const float*)d_in[36];
  const float* bd2 = (const float*)d_in[37];
  const float* lnd2_s = (const float*)d_in[38];
  const float* lnd2_b = (const float*)d_in[39];
  const float* Wout = (const float*)d_in[40];
  const float* bout = (const float*)d_in[41];
  (void)in_sizes; (void)n_in; (void)out_size; (void)ws_size;

  float* ws = (float*)d_ws;
  float* X = ws;                // 4718592
  float* Yb = ws + NX;          // 4718592
  float* Gb = ws + 2 * NX;      // 9437184
  float* Cb = Gb + NG;          // 4718592
  float* Qb = Gb;               // qkv reuse G after GRU phases
  float* Kb = Gb + TOK * QKVN;
  float* Vb = Gb + 2 * TOK * QKVN;
  float* AO = Cb;

  const int TB = TOK / 32;      // 576

  inproj_ln<<<TOK, 256, 0, stream>>>(x_cgm, W_in, b_in, ln0_s, ln0_b, X);

  // GRU block 0
  gemm_bias<1, 256, 0><<<dim3(TB, 2), 256, 0, stream>>>(X, g0_Wg, g0_bg, nullptr, Gb, 256, 512);
  gemm_bias<0, 256, 0><<<dim3(TB, 1), 256, 0, stream>>>(X, g0_Wcx, g0_bcx, nullptr, Cb, 256, 256);
  gru_scan<<<B_, 256, 0, stream>>>(Gb, Cb, g0_Wch, g0_bch, Yb);
  ln_token<1><<<TOK, 256, 0, stream>>>(Yb, ln1_s, ln1_b, X, X);

  // GRU block 1
  gemm_bias<1, 256, 0><<<dim3(TB, 2), 256, 0, stream>>>(X, g1_Wg, g1_bg, nullptr, Gb, 256, 512);
  gemm_bias<0, 256, 0><<<dim3(TB, 1), 256, 0, stream>>>(X, g1_Wcx, g1_bcx, nullptr, Cb, 256, 256);
  gru_scan<<<B_, 256, 0, stream>>>(Gb, Cb, g1_Wch, g1_bch, Yb);
  ln_token<1><<<TOK, 256, 0, stream>>>(Yb, ln2_s, ln2_b, X, X);

  // attention
  ln_token<0><<<TOK, 256, 0, stream>>>(X, aln_s, aln_b, nullptr, Yb);
  gemm_bias<0, 64, 0><<<dim3(TB, 1), 256, 0, stream>>>(Yb, Wq, bq, nullptr, Qb, 256, 64);
  gemm_bias<0, 64, 0><<<dim3(TB, 1), 256, 0, stream>>>(Yb, Wk, bk, nullptr, Kb, 256, 64);
  gemm_bias<0, 64, 0><<<dim3(TB, 1), 256, 0, stream>>>(Yb, Wv, bv, nullptr, Vb, 256, 64);
  attn<<<dim3(B_, 4), 320, 0, stream>>>(Qb, Kb, Vb, AO);
  gemm_bias<0, 256, 1><<<dim3(TB, 1), 256, 0, stream>>>(AO, Wo, bo, X, X, 64, 256);

  // head
  head<<<B_, 128, 0, stream>>>(X, x_other, Wd1, bd1, lnd1_s, lnd1_b,
                               Wd2, bd2, lnd2_s, lnd2_b, Wout, bout,
                               (float*)d_out);
}

// Round 2
// 1314.508 us; speedup vs baseline: 1.9542x; 1.9542x over previous
//
#include <hip/hip_runtime.h>
#include <math.h>

// GRUModel: B=64,S=288,Fc=16,Fo=32,D=256,QKV=64,HEADS=4,hd=16
// Round 2: gru_scan rewritten — Wch held in VGPRs (64 regs/thread, 1024 thr),
// v distributed via readlane->SGPR, zero W traffic per step.
// ws layout (floats): X[18432*256] | Y[18432*256] | G[18432*512] | C[18432*256]

#define EPS 1e-5f
constexpr int B_ = 64, S_ = 288, FC = 16, FO = 32, D_ = 256, QKVN = 64, HD = 16;
constexpr int TOK = B_ * S_;            // 18432
constexpr int NX = TOK * D_;            // 4718592
constexpr int NG = TOK * 512;           // 9437184

// block-wide sum; blockDim multiple of 64, <=512. sc: >= blockDim/64 floats.
__device__ __forceinline__ float blk_sum(float v, float* sc) {
  #pragma unroll
  for (int o = 32; o > 0; o >>= 1) v += __shfl_down(v, o, 64);
  int tid = threadIdx.x;
  int wid = tid >> 6, nw = blockDim.x >> 6;
  __syncthreads();                      // protect sc from previous use
  if ((tid & 63) == 0) sc[wid] = v;
  __syncthreads();
  float s = 0.f;
  for (int w = 0; w < nw; ++w) s += sc[w];
  return s;
}

// ---------------- input projection + LN0: one block per token, 256 thr -------
__global__ __launch_bounds__(256) void inproj_ln(
    const float* __restrict__ xc, const float* __restrict__ Wi,
    const float* __restrict__ bi, const float* __restrict__ sc_,
    const float* __restrict__ bb, float* __restrict__ X) {
  __shared__ float sc[8];
  int tok = blockIdx.x, j = threadIdx.x;
  const float* xr = xc + tok * FC;
  float acc = bi[j];
  #pragma unroll
  for (int i = 0; i < FC; ++i) acc += xr[i] * Wi[i * D_ + j];
  float m = blk_sum(acc, sc) * (1.f / D_);
  float d = acc - m;
  float var = blk_sum(d * d, sc) * (1.f / D_);
  X[tok * D_ + j] = d * rsqrtf(var + EPS) * sc_[j] + bb[j];
}

// ---------------- LN over D=256 per token, optional residual add -------------
template <int RES>
__global__ __launch_bounds__(256) void ln_token(
    const float* __restrict__ in, const float* __restrict__ sc_,
    const float* __restrict__ bb, const float* __restrict__ resid,
    float* __restrict__ out) {
  __shared__ float sc[8];
  int tok = blockIdx.x, j = threadIdx.x;
  float v = in[tok * D_ + j];
  float m = blk_sum(v, sc) * (1.f / D_);
  float d = v - m;
  float var = blk_sum(d * d, sc) * (1.f / D_);
  float r = d * rsqrtf(var + EPS) * sc_[j] + bb[j];
  if (RES) r += resid[tok * D_ + j];
  out[tok * D_ + j] = r;
}

// ---------------- generic fp32 GEMM: OUT[M,N] = act(A[M,K]@W[K,N]+b)(+resid) -
// TM=32 rows/block, 256 threads. NC = cols handled per block (256 or 64).
// grid = (M/32, N/NC). K runtime (256 or 64), divisible by 4.
template <int ACT, int NC, int RES>
__global__ __launch_bounds__(256) void gemm_bias(
    const float* __restrict__ A, const float* __restrict__ W,
    const float* __restrict__ bias, const float* __restrict__ resid,
    float* __restrict__ OUT, int K, int N) {
  constexpr int TM = 32;
  constexpr int NT = TM * NC / 256;     // rows per thread
  __shared__ float4 As4[TM * 64];       // up to 32x256 fp32 = 32KB
  int row0 = blockIdx.x * TM;
  int tid = threadIdx.x;
  const float4* Ag = (const float4*)(A + (size_t)row0 * K);
  int n4 = TM * K / 4;
  for (int i = tid; i < n4; i += 256) As4[i] = Ag[i];
  __syncthreads();
  int col = blockIdx.y * NC + (tid % NC);
  int rg = tid / NC;
  int t0 = rg * NT;
  float bv = bias[col];
  float acc[NT];
  #pragma unroll
  for (int t = 0; t < NT; ++t) acc[t] = bv;
  int K4 = K >> 2;
  for (int k0 = 0; k0 < K4; ++k0) {
    float w0 = W[(k0 * 4 + 0) * N + col];
    float w1 = W[(k0 * 4 + 1) * N + col];
    float w2 = W[(k0 * 4 + 2) * N + col];
    float w3 = W[(k0 * 4 + 3) * N + col];
    #pragma unroll
    for (int t = 0; t < NT; ++t) {
      float4 a = As4[(t0 + t) * K4 + k0];
      acc[t] += a.x * w0 + a.y * w1 + a.z * w2 + a.w * w3;
    }
  }
  #pragma unroll
  for (int t = 0; t < NT; ++t) {
    int row = row0 + t0 + t;
    float v = acc[t];
    if (ACT == 1) v = 1.f / (1.f + __expf(-v));
    if (RES) v += resid[(size_t)row * N + col];
    OUT[(size_t)row * N + col] = v;
  }
}

// ---------------- GRU sequential scan v2: 1 block/batch, 1024 thr ----------
// Wch kept in VGPRs: thread (kc=tid>>7 in [0,8), c2=tid&127) holds
// W[32*kc + j][2*c2 + {0,1}] for j in [0,32) -> wA[32], wB[32].
// Per step: v=r*h staged in LDS (256 f); each wave: lanes 0..31 do ONE
// ds_read_b32 of its 32 v's, then 32x v_readlane -> SGPR, 64x v_fmac.
// Partials lp[8][258] reduced by owner threads (tid<256). r/u/c prefetched.
__global__ __launch_bounds__(1024, 4) void gru_scan(
    const float* __restrict__ G, const float* __restrict__ C,
    const float* __restrict__ Wch, const float* __restrict__ bch,
    float* __restrict__ Y) {
  __shared__ float lv[256];
  __shared__ float lp[8][258];          // pad 258: owner reads conflict-free
  int tid = threadIdx.x;
  int b = blockIdx.x;
  int kc = tid >> 7;                    // 0..7 (32 k-rows each)
  int c2 = tid & 127;                   // column pair index
  int lane = tid & 63;

  // one-time W preload into registers (L2 stream, coalesced float2)
  float wA[32], wB[32];
  {
    const float* Wp = Wch + (32 * kc) * D_ + 2 * c2;
    #pragma unroll
    for (int j = 0; j < 32; ++j) {
      float2 w = *(const float2*)(Wp + j * D_);
      wA[j] = w.x; wB[j] = w.y;
    }
  }

  bool owner = tid < 256;
  int col = tid;                        // valid when owner
  float h = 0.f;
  float bchv = 0.f, u_cur = 0.f, c_cur = 0.f, r_w = 0.f;
  const float* Gp = G + (size_t)b * S_ * 512;
  const float* Cp = C + (size_t)b * S_ * 256;
  float* Yp = Y + (size_t)b * S_ * 256;
  if (owner) {
    bchv = bch[col];
    u_cur = Gp[256 + col];              // u_0
    c_cur = Cp[col];                    // c_0
    r_w = Gp[512 + col];                // r_1 (S_>1)
    lv[col] = 0.f;                      // v_0 = r_0 * h_{-1} = 0
  }
  __syncthreads();

  for (int t = 0; t < S_; ++t) {
    // fetch this wave's 32 v values: lanes 0..31 (dup on 32..63), conflict-free
    float vfetch = lv[32 * kc + (lane & 31)];

    // prefetch next step's gate/candidate streams (full step of slack)
    float u_n = 0.f, c_n = 0.f, r_n = 0.f;
    if (owner) {
      if (t + 1 < S_) {
        u_n = Gp[(size_t)(t + 1) * 512 + 256 + col];
        c_n = Cp[(size_t)(t + 1) * 256 + col];
      }
      if (t + 2 < S_) r_n = Gp[(size_t)(t + 2) * 512 + col];
    }

    // inner product: v (wave-uniform via readlane) x W (registers)
    float a0 = 0.f, a1 = 0.f;
    #pragma unroll
    for (int j = 0; j < 32; ++j) {
      float vj = __int_as_float(
          __builtin_amdgcn_readlane(__float_as_int(vfetch), j));
      a0 += vj * wA[j];
      a1 += vj * wB[j];
    }
    *(float2*)&lp[kc][2 * c2] = make_float2(a0, a1);
    __syncthreads();                    // lp ready; all lv reads of step t done

    if (owner) {
      float s = c_cur + bchv;
      #pragma unroll
      for (int j = 0; j < 8; ++j) s += lp[j][col];
      float cand = tanhf(s);
      h = u_cur * h + (1.f - u_cur) * cand;
      Yp[(size_t)t * 256 + col] = h;
      lv[col] = r_w * h;                // v_{t+1} = r_{t+1} * h_t
      u_cur = u_n; c_cur = c_n; r_w = r_n;
    }
    __syncthreads();                    // lv ready for step t+1
  }
}

// ---------------- flash attention: block=(b,head), 320 thr, K/V in LDS -------
__global__ __launch_bounds__(320) void attn(
    const float* __restrict__ Q, const float* __restrict__ Kv,
    const float* __restrict__ V, float* __restrict__ AO) {
  __shared__ float Kl[S_ * HD];
  __shared__ float Vl[S_ * HD];
  int b = blockIdx.x, hh = blockIdx.y;
  int tid = threadIdx.x;
  int hoff = hh * HD;
  for (int idx = tid; idx < S_ * HD; idx += 320) {
    int row = idx >> 4, d = idx & 15;
    Kl[idx] = Kv[((size_t)(b * S_ + row)) * QKVN + hoff + d];
    Vl[idx] = V[((size_t)(b * S_ + row)) * QKVN + hoff + d];
  }
  __syncthreads();
  if (tid >= S_) return;
  const float* qp = Q + ((size_t)(b * S_ + tid)) * QKVN + hoff;
  float4 q0 = *(const float4*)(qp + 0);
  float4 q1 = *(const float4*)(qp + 4);
  float4 q2 = *(const float4*)(qp + 8);
  float4 q3 = *(const float4*)(qp + 12);
  float m = -1e30f, l = 0.f;
  float4 o0 = {0, 0, 0, 0}, o1 = {0, 0, 0, 0}, o2 = {0, 0, 0, 0},
         o3 = {0, 0, 0, 0};
  for (int k = 0; k < S_; ++k) {
    const float4* kp = (const float4*)&Kl[k * HD];
    float4 k0 = kp[0], k1 = kp[1], k2 = kp[2], k3 = kp[3];
    float s = q0.x * k0.x + q0.y * k0.y + q0.z * k0.z + q0.w * k0.w +
              q1.x * k1.x + q1.y * k1.y + q1.z * k1.z + q1.w * k1.w +
              q2.x * k2.x + q2.y * k2.y + q2.z * k2.z + q2.w * k2.w +
              q3.x * k3.x + q3.y * k3.y + q3.z * k3.z + q3.w * k3.w;
    s *= 0.25f;                          // 1/sqrt(16)
    float mn = fmaxf(m, s);
    float corr = __expf(m - mn);
    float p = __expf(s - mn);
    l = l * corr + p;
    const float4* vp = (const float4*)&Vl[k * HD];
    float4 v0 = vp[0], v1 = vp[1], v2 = vp[2], v3 = vp[3];
    o0.x = o0.x * corr + p * v0.x; o0.y = o0.y * corr + p * v0.y;
    o0.z = o0.z * corr + p * v0.z; o0.w = o0.w * corr + p * v0.w;
    o1.x = o1.x * corr + p * v1.x; o1.y = o1.y * corr + p * v1.y;
    o1.z = o1.z * corr + p * v1.z; o1.w = o1.w * corr + p * v1.w;
    o2.x = o2.x * corr + p * v2.x; o2.y = o2.y * corr + p * v2.y;
    o2.z = o2.z * corr + p * v2.z; o2.w = o2.w * corr + p * v2.w;
    o3.x = o3.x * corr + p * v3.x; o3.y = o3.y * corr + p * v3.y;
    o3.z = o3.z * corr + p * v3.z; o3.w = o3.w * corr + p * v3.w;
    m = mn;
  }
  float inv = 1.f / l;
  float* op = AO + ((size_t)(b * S_ + tid)) * QKVN + hoff;
  float4 r0 = {o0.x * inv, o0.y * inv, o0.z * inv, o0.w * inv};
  float4 r1 = {o1.x * inv, o1.y * inv, o1.z * inv, o1.w * inv};
  float4 r2 = {o2.x * inv, o2.y * inv, o2.z * inv, o2.w * inv};
  float4 r3 = {o3.x * inv, o3.y * inv, o3.z * inv, o3.w * inv};
  ((float4*)op)[0] = r0; ((float4*)op)[1] = r1;
  ((float4*)op)[2] = r2; ((float4*)op)[3] = r3;
}

// ---------------- head: pool + concat + d1(LN) + d2(LN) + out ----------------
__global__ __launch_bounds__(128) void head(
    const float* __restrict__ X, const float* __restrict__ xo,
    const float* __restrict__ Wd1, const float* __restrict__ bd1,
    const float* __restrict__ s1, const float* __restrict__ b1,
    const float* __restrict__ Wd2, const float* __restrict__ bd2,
    const float* __restrict__ s2, const float* __restrict__ b2,
    const float* __restrict__ Wout, const float* __restrict__ bout,
    float* __restrict__ out) {
  __shared__ float c[D_ + FO];
  __shared__ float h1[128];
  __shared__ float sc[8];
  int b = blockIdx.x, tid = threadIdx.x;
  for (int cc = tid; cc < D_; cc += 128) {
    float acc = 0.f;
    for (int t = 0; t < S_; ++t) acc += X[((size_t)(b * S_ + t)) * D_ + cc];
    c[cc] = acc * (1.f / S_);
  }
  if (tid < FO) c[D_ + tid] = xo[b * FO + tid];
  __syncthreads();
  // dense1 (128 outputs) + relu + LN
  float v = bd1[tid];
  for (int k = 0; k < D_ + FO; ++k) v += c[k] * Wd1[k * 128 + tid];
  v = fmaxf(v, 0.f);
  float m = blk_sum(v, sc) * (1.f / 128.f);
  float d = v - m;
  float var = blk_sum(d * d, sc) * (1.f / 128.f);
  h1[tid] = d * rsqrtf(var + EPS) * s1[tid] + b1[tid];
  __syncthreads();
  // dense2 (64 outputs) + relu + LN
  float v2 = 0.f;
  if (tid < 64) {
    v2 = bd2[tid];
    for (int k = 0; k < 128; ++k) v2 += h1[k] * Wd2[k * 64 + tid];
    v2 = fmaxf(v2, 0.f);
  }
  float m2 = blk_sum(tid < 64 ? v2 : 0.f, sc) * (1.f / 64.f);
  float d2v = v2 - m2;
  float var2 = blk_sum(tid < 64 ? d2v * d2v : 0.f, sc) * (1.f / 64.f);
  float hv = (tid < 64) ? (d2v * rsqrtf(var2 + EPS) * s2[tid] + b2[tid]) : 0.f;
  float p = (tid < 64) ? hv * Wout[tid] : 0.f;
  float tot = blk_sum(p, sc);
  if (tid == 0) out[b] = tot + bout[0];
}

extern "C" void kernel_launch(void* const* d_in, const int* in_sizes, int n_in,
                              void* d_out, int out_size, void* d_ws,
                              size_t ws_size, hipStream_t stream) {
  const float* x_cgm = (const float*)d_in[0];
  const float* x_other = (const float*)d_in[1];
  const float* W_in = (const float*)d_in[2];
  const float* b_in = (const float*)d_in[3];
  const float* ln0_s = (const float*)d_in[4];
  const float* ln0_b = (const float*)d_in[5];
  const float* g0_Wg = (const float*)d_in[6];
  const float* g0_bg = (const float*)d_in[7];
  const float* g0_Wcx = (const float*)d_in[8];
  const float* g0_bcx = (const float*)d_in[9];
  const float* g0_Wch = (const float*)d_in[10];
  const float* g0_bch = (const float*)d_in[11];
  const float* g1_Wg = (const float*)d_in[12];
  const float* g1_bg = (const float*)d_in[13];
  const float* g1_Wcx = (const float*)d_in[14];
  const float* g1_bcx = (const float*)d_in[15];
  const float* g1_Wch = (const float*)d_in[16];
  const float* g1_bch = (const float*)d_in[17];
  const float* ln1_s = (const float*)d_in[18];
  const float* ln1_b = (const float*)d_in[19];
  const float* ln2_s = (const float*)d_in[20];
  const float* ln2_b = (const float*)d_in[21];
  const float* aln_s = (const float*)d_in[22];
  const float* aln_b = (const float*)d_in[23];
  const float* Wq = (const float*)d_in[24];
  const float* Wk = (const float*)d_in[25];
  const float* Wv = (const float*)d_in[26];
  const float* bq = (const float*)d_in[27];
  const float* bk = (const float*)d_in[28];
  const float* bv = (const float*)d_in[29];
  const float* Wo = (const float*)d_in[30];
  const float* bo = (const float*)d_in[31];
  const float* Wd1 = (const float*)d_in[32];
  const float* bd1 = (const float*)d_in[33];
  const float* lnd1_s = (const float*)d_in[34];
  const float* lnd1_b = (const float*)d_in[35];
  const float* Wd2 = (const float*)d_in[36];
  const float* bd2 = (const float*)d_in[37];
  const float* lnd2_s = (const float*)d_in[38];
  const float* lnd2_b = (const float*)d_in[39];
  const float* Wout = (const float*)d_in[40];
  const float* bout = (const float*)d_in[41];
  (void)in_sizes; (void)n_in; (void)out_size; (void)ws_size;

  float* ws = (float*)d_ws;
  float* X = ws;                // 4718592
  float* Yb = ws + NX;          // 4718592
  float* Gb = ws + 2 * NX;      // 9437184
  float* Cb = Gb + NG;          // 4718592
  float* Qb = Gb;               // qkv reuse G after GRU phases
  float* Kb = Gb + TOK * QKVN;
  float* Vb = Gb + 2 * TOK * QKVN;
  float* AO = Cb;

  const int TB = TOK / 32;      // 576

  inproj_ln<<<TOK, 256, 0, stream>>>(x_cgm, W_in, b_in, ln0_s, ln0_b, X);

  // GRU block 0
  gemm_bias<1, 256, 0><<<dim3(TB, 2), 256, 0, stream>>>(X, g0_Wg, g0_bg, nullptr, Gb, 256, 512);
  gemm_bias<0, 256, 0><<<dim3(TB, 1), 256, 0, stream>>>(X, g0_Wcx, g0_bcx, nullptr, Cb, 256, 256);
  gru_scan<<<B_, 1024, 0, stream>>>(Gb, Cb, g0_Wch, g0_bch, Yb);
  ln_token<1><<<TOK, 256, 0, stream>>>(Yb, ln1_s, ln1_b, X, X);

  // GRU block 1
  gemm_bias<1, 256, 0><<<dim3(TB, 2), 256, 0, stream>>>(X, g1_Wg, g1_bg, nullptr, Gb, 256, 512);
  gemm_bias<0, 256, 0><<<dim3(TB, 1), 256, 0, stream>>>(X, g1_Wcx, g1_bcx, nullptr, Cb, 256, 256);
  gru_scan<<<B_, 1024, 0, stream>>>(Gb, Cb, g1_Wch, g1_bch, Yb);
  ln_token<1><<<TOK, 256, 0, stream>>>(Yb, ln2_s, ln2_b, X, X);

  // attention
  ln_token<0><<<TOK, 256, 0, stream>>>(X, aln_s, aln_b, nullptr, Yb);
  gemm_bias<0, 64, 0><<<dim3(TB, 1), 256, 0, stream>>>(Yb, Wq, bq, nullptr, Qb, 256, 64);
  gemm_bias<0, 64, 0><<<dim3(TB, 1), 256, 0, stream>>>(Yb, Wk, bk, nullptr, Kb, 256, 64);
  gemm_bias<0, 64, 0><<<dim3(TB, 1), 256, 0, stream>>>(Yb, Wv, bv, nullptr, Vb, 256, 64);
  attn<<<dim3(B_, 4), 320, 0, stream>>>(Qb, Kb, Vb, AO);
  gemm_bias<0, 256, 1><<<dim3(TB, 1), 256, 0, stream>>>(AO, Wo, bo, X, X, 64, 256);

  // head
  head<<<B_, 128, 0, stream>>>(X, x_other, Wd1, bd1, lnd1_s, lnd1_b,
                               Wd2, bd2, lnd2_s, lnd2_b, Wout, bout,
                               (float*)d_out);
}

// Round 3
// 888.930 us; speedup vs baseline: 2.8898x; 1.4788x over previous
//
#include <hip/hip_runtime.h>
#include <hip/hip_bf16.h>
#include <math.h>

// GRUModel: B=64,S=288,Fc=16,Fo=32,D=256,QKV=64,HEADS=4,hd=16
// Round 3: all big GEMMs -> bf16 MFMA (16x16x32), fp32 accumulate.
// fp32->bf16 conversion happens during LDS staging; no extra ws, no layout
// changes elsewhere. Scan/LN/attn/head identical to round 2.
// ws layout (floats): X[18432*256] | Y[18432*256] | G[18432*512] | C[18432*256]

#define EPS 1e-5f
constexpr int B_ = 64, S_ = 288, FC = 16, FO = 32, D_ = 256, QKVN = 64, HD = 16;
constexpr int TOK = B_ * S_;            // 18432
constexpr int NX = TOK * D_;            // 4718592
constexpr int NG = TOK * 512;           // 9437184

typedef short bf16x8 __attribute__((ext_vector_type(8)));
typedef float f32x4 __attribute__((ext_vector_type(4)));

__device__ __forceinline__ short f2bf(float f) {
  __hip_bfloat16 h = __float2bfloat16(f);
  return __builtin_bit_cast(short, h);
}

// block-wide sum; blockDim multiple of 64, <=512. sc: >= blockDim/64 floats.
__device__ __forceinline__ float blk_sum(float v, float* sc) {
  #pragma unroll
  for (int o = 32; o > 0; o >>= 1) v += __shfl_down(v, o, 64);
  int tid = threadIdx.x;
  int wid = tid >> 6, nw = blockDim.x >> 6;
  __syncthreads();                      // protect sc from previous use
  if ((tid & 63) == 0) sc[wid] = v;
  __syncthreads();
  float s = 0.f;
  for (int w = 0; w < nw; ++w) s += sc[w];
  return s;
}

// ---------------- input projection + LN0: one block per token, 256 thr -------
__global__ __launch_bounds__(256) void inproj_ln(
    const float* __restrict__ xc, const float* __restrict__ Wi,
    const float* __restrict__ bi, const float* __restrict__ sc_,
    const float* __restrict__ bb, float* __restrict__ X) {
  __shared__ float sc[8];
  int tok = blockIdx.x, j = threadIdx.x;
  const float* xr = xc + tok * FC;
  float acc = bi[j];
  #pragma unroll
  for (int i = 0; i < FC; ++i) acc += xr[i] * Wi[i * D_ + j];
  float m = blk_sum(acc, sc) * (1.f / D_);
  float d = acc - m;
  float var = blk_sum(d * d, sc) * (1.f / D_);
  X[tok * D_ + j] = d * rsqrtf(var + EPS) * sc_[j] + bb[j];
}

// ---------------- LN over D=256 per token, optional residual add -------------
template <int RES>
__global__ __launch_bounds__(256) void ln_token(
    const float* __restrict__ in, const float* __restrict__ sc_,
    const float* __restrict__ bb, const float* __restrict__ resid,
    float* __restrict__ out) {
  __shared__ float sc[8];
  int tok = blockIdx.x, j = threadIdx.x;
  float v = in[tok * D_ + j];
  float m = blk_sum(v, sc) * (1.f / D_);
  float d = v - m;
  float var = blk_sum(d * d, sc) * (1.f / D_);
  float r = d * rsqrtf(var + EPS) * sc_[j] + bb[j];
  if (RES) r += resid[tok * D_ + j];
  out[tok * D_ + j] = r;
}

// ---------------- bf16 MFMA GEMM: OUT[M,N] = act(A@W + b)(+resid) -----------
// A fp32 [M,K] row-major, W fp32 [K,N] row-major; both cast to bf16 during LDS
// staging; fp32 accumulate. BM=128, BK=32, 256 thr (4 waves). Each wave owns a
// 32-row strip x BN cols = 2 x (BN/16) 16x16 C-tiles.
// LDS: As[row][k] stride 40 (pad: 2-way max bank alias = free);
//      Bs[n][k]  stride 40 (n-major so B-frag reads are ds_read_b128).
// grid = (M/128, N/BN). K in {256, 64}.
template <int BN, int ACT, int RES>
__global__ __launch_bounds__(256) void gemm_mfma(
    const float* __restrict__ A, const float* __restrict__ W,
    const float* __restrict__ bias, const float* __restrict__ resid,
    float* __restrict__ OUT, int K, int N) {
  constexpr int BM = 128, BK = 32;
  constexpr int NT16 = BN / 16;         // n-tiles per wave
  constexpr int BTASK = BN * 4 / 256;   // B staging tasks per thread
  __shared__ short As[BM * 40];
  __shared__ short Bs[BN * 40];
  int tid = threadIdx.x;
  int wave = tid >> 6, lane = tid & 63;
  int quad = lane >> 4, m16 = lane & 15;
  int row0 = blockIdx.x * BM;
  int bn0 = blockIdx.y * BN;

  f32x4 acc[2][NT16];
  #pragma unroll
  for (int mt = 0; mt < 2; ++mt)
    #pragma unroll
    for (int nt = 0; nt < NT16; ++nt) acc[mt][nt] = (f32x4){0.f, 0.f, 0.f, 0.f};

  const float* Ag = A + (size_t)row0 * K;

  for (int kk = 0; kk < K; kk += BK) {
    __syncthreads();                    // previous compute done before restage
    // ---- stage A tile 128x32: 1024 float4 tasks, 4/thread ----
    #pragma unroll
    for (int i = 0; i < 4; ++i) {
      int t = tid + i * 256;
      int r = t >> 3, kq = t & 7;       // row, k-quad (4 floats)
      float4 a4 = *(const float4*)(Ag + (size_t)r * K + kk + kq * 4);
      short4 s4 = make_short4(f2bf(a4.x), f2bf(a4.y), f2bf(a4.z), f2bf(a4.w));
      *(short4*)&As[r * 40 + kq * 4] = s4;
    }
    // ---- stage B tile 32xBN (n-major): BN*4 oct tasks ----
    #pragma unroll
    for (int i = 0; i < BTASK; ++i) {
      int t = tid + i * 256;
      int n = t % BN, oct = t / BN;     // 8 consecutive k per task
      const float* bp = W + (size_t)(kk + oct * 8) * N + bn0 + n;
      bf16x8 bv;
      #pragma unroll
      for (int j = 0; j < 8; ++j) bv[j] = f2bf(bp[(size_t)j * N]);
      *(bf16x8*)&Bs[n * 40 + oct * 8] = bv;
    }
    __syncthreads();
    // ---- MFMA: A[m=lane&15][k=quad*8+j], B[k=quad*8+j][n=lane&15] ----
    bf16x8 af0 = *(const bf16x8*)&As[(wave * 32 + m16) * 40 + quad * 8];
    bf16x8 af1 = *(const bf16x8*)&As[(wave * 32 + 16 + m16) * 40 + quad * 8];
    #pragma unroll
    for (int nt = 0; nt < NT16; ++nt) {
      bf16x8 bfr = *(const bf16x8*)&Bs[(nt * 16 + m16) * 40 + quad * 8];
      acc[0][nt] = __builtin_amdgcn_mfma_f32_16x16x32_bf16(af0, bfr, acc[0][nt], 0, 0, 0);
      acc[1][nt] = __builtin_amdgcn_mfma_f32_16x16x32_bf16(af1, bfr, acc[1][nt], 0, 0, 0);
    }
  }
  // ---- epilogue: C/D layout col=lane&15, row=quad*4+reg ----
  #pragma unroll
  for (int mt = 0; mt < 2; ++mt) {
    #pragma unroll
    for (int nt = 0; nt < NT16; ++nt) {
      int col = bn0 + nt * 16 + m16;
      float bv = bias[col];
      #pragma unroll
      for (int r = 0; r < 4; ++r) {
        int row = row0 + wave * 32 + mt * 16 + quad * 4 + r;
        float v = acc[mt][nt][r] + bv;
        if (ACT == 1) v = 1.f / (1.f + __expf(-v));
        if (RES) v += resid[(size_t)row * N + col];
        OUT[(size_t)row * N + col] = v;
      }
    }
  }
}

// ---------------- GRU sequential scan v2: 1 block/batch, 1024 thr ----------
// Wch kept in VGPRs: thread (kc=tid>>7 in [0,8), c2=tid&127) holds
// W[32*kc + j][2*c2 + {0,1}] for j in [0,32) -> wA[32], wB[32].
// Per step: v=r*h staged in LDS (256 f); each wave: lanes 0..31 do ONE
// ds_read_b32 of its 32 v's, then 32x v_readlane -> SGPR, 64x v_fmac.
// Partials lp[8][258] reduced by owner threads (tid<256). r/u/c prefetched.
__global__ __launch_bounds__(1024, 4) void gru_scan(
    const float* __restrict__ G, const float* __restrict__ C,
    const float* __restrict__ Wch, const float* __restrict__ bch,
    float* __restrict__ Y) {
  __shared__ float lv[256];
  __shared__ float lp[8][258];          // pad 258: owner reads conflict-free
  int tid = threadIdx.x;
  int b = blockIdx.x;
  int kc = tid >> 7;                    // 0..7 (32 k-rows each)
  int c2 = tid & 127;                   // column pair index
  int lane = tid & 63;

  // one-time W preload into registers (L2 stream, coalesced float2)
  float wA[32], wB[32];
  {
    const float* Wp = Wch + (32 * kc) * D_ + 2 * c2;
    #pragma unroll
    for (int j = 0; j < 32; ++j) {
      float2 w = *(const float2*)(Wp + j * D_);
      wA[j] = w.x; wB[j] = w.y;
    }
  }

  bool owner = tid < 256;
  int col = tid;                        // valid when owner
  float h = 0.f;
  float bchv = 0.f, u_cur = 0.f, c_cur = 0.f, r_w = 0.f;
  const float* Gp = G + (size_t)b * S_ * 512;
  const float* Cp = C + (size_t)b * S_ * 256;
  float* Yp = Y + (size_t)b * S_ * 256;
  if (owner) {
    bchv = bch[col];
    u_cur = Gp[256 + col];              // u_0
    c_cur = Cp[col];                    // c_0
    r_w = Gp[512 + col];                // r_1 (S_>1)
    lv[col] = 0.f;                      // v_0 = r_0 * h_{-1} = 0
  }
  __syncthreads();

  for (int t = 0; t < S_; ++t) {
    // fetch this wave's 32 v values: lanes 0..31 (dup on 32..63), conflict-free
    float vfetch = lv[32 * kc + (lane & 31)];

    // prefetch next step's gate/candidate streams (full step of slack)
    float u_n = 0.f, c_n = 0.f, r_n = 0.f;
    if (owner) {
      if (t + 1 < S_) {
        u_n = Gp[(size_t)(t + 1) * 512 + 256 + col];
        c_n = Cp[(size_t)(t + 1) * 256 + col];
      }
      if (t + 2 < S_) r_n = Gp[(size_t)(t + 2) * 512 + col];
    }

    // inner product: v (wave-uniform via readlane) x W (registers)
    float a0 = 0.f, a1 = 0.f;
    #pragma unroll
    for (int j = 0; j < 32; ++j) {
      float vj = __int_as_float(
          __builtin_amdgcn_readlane(__float_as_int(vfetch), j));
      a0 += vj * wA[j];
      a1 += vj * wB[j];
    }
    *(float2*)&lp[kc][2 * c2] = make_float2(a0, a1);
    __syncthreads();                    // lp ready; all lv reads of step t done

    if (owner) {
      float s = c_cur + bchv;
      #pragma unroll
      for (int j = 0; j < 8; ++j) s += lp[j][col];
      float cand = tanhf(s);
      h = u_cur * h + (1.f - u_cur) * cand;
      Yp[(size_t)t * 256 + col] = h;
      lv[col] = r_w * h;                // v_{t+1} = r_{t+1} * h_t
      u_cur = u_n; c_cur = c_n; r_w = r_n;
    }
    __syncthreads();                    // lv ready for step t+1
  }
}

// ---------------- flash attention: block=(b,head), 320 thr, K/V in LDS -------
__global__ __launch_bounds__(320) void attn(
    const float* __restrict__ Q, const float* __restrict__ Kv,
    const float* __restrict__ V, float* __restrict__ AO) {
  __shared__ float Kl[S_ * HD];
  __shared__ float Vl[S_ * HD];
  int b = blockIdx.x, hh = blockIdx.y;
  int tid = threadIdx.x;
  int hoff = hh * HD;
  for (int idx = tid; idx < S_ * HD; idx += 320) {
    int row = idx >> 4, d = idx & 15;
    Kl[idx] = Kv[((size_t)(b * S_ + row)) * QKVN + hoff + d];
    Vl[idx] = V[((size_t)(b * S_ + row)) * QKVN + hoff + d];
  }
  __syncthreads();
  if (tid >= S_) return;
  const float* qp = Q + ((size_t)(b * S_ + tid)) * QKVN + hoff;
  float4 q0 = *(const float4*)(qp + 0);
  float4 q1 = *(const float4*)(qp + 4);
  float4 q2 = *(const float4*)(qp + 8);
  float4 q3 = *(const float4*)(qp + 12);
  float m = -1e30f, l = 0.f;
  float4 o0 = {0, 0, 0, 0}, o1 = {0, 0, 0, 0}, o2 = {0, 0, 0, 0},
         o3 = {0, 0, 0, 0};
  for (int k = 0; k < S_; ++k) {
    const float4* kp = (const float4*)&Kl[k * HD];
    float4 k0 = kp[0], k1 = kp[1], k2 = kp[2], k3 = kp[3];
    float s = q0.x * k0.x + q0.y * k0.y + q0.z * k0.z + q0.w * k0.w +
              q1.x * k1.x + q1.y * k1.y + q1.z * k1.z + q1.w * k1.w +
              q2.x * k2.x + q2.y * k2.y + q2.z * k2.z + q2.w * k2.w +
              q3.x * k3.x + q3.y * k3.y + q3.z * k3.z + q3.w * k3.w;
    s *= 0.25f;                          // 1/sqrt(16)
    float mn = fmaxf(m, s);
    float corr = __expf(m - mn);
    float p = __expf(s - mn);
    l = l * corr + p;
    const float4* vp = (const float4*)&Vl[k * HD];
    float4 v0 = vp[0], v1 = vp[1], v2 = vp[2], v3 = vp[3];
    o0.x = o0.x * corr + p * v0.x; o0.y = o0.y * corr + p * v0.y;
    o0.z = o0.z * corr + p * v0.z; o0.w = o0.w * corr + p * v0.w;
    o1.x = o1.x * corr + p * v1.x; o1.y = o1.y * corr + p * v1.y;
    o1.z = o1.z * corr + p * v1.z; o1.w = o1.w * corr + p * v1.w;
    o2.x = o2.x * corr + p * v2.x; o2.y = o2.y * corr + p * v2.y;
    o2.z = o2.z * corr + p * v2.z; o2.w = o2.w * corr + p * v2.w;
    o3.x = o3.x * corr + p * v3.x; o3.y = o3.y * corr + p * v3.y;
    o3.z = o3.z * corr + p * v3.z; o3.w = o3.w * corr + p * v3.w;
    m = mn;
  }
  float inv = 1.f / l;
  float* op = AO + ((size_t)(b * S_ + tid)) * QKVN + hoff;
  float4 r0 = {o0.x * inv, o0.y * inv, o0.z * inv, o0.w * inv};
  float4 r1 = {o1.x * inv, o1.y * inv, o1.z * inv, o1.w * inv};
  float4 r2 = {o2.x * inv, o2.y * inv, o2.z * inv, o2.w * inv};
  float4 r3 = {o3.x * inv, o3.y * inv, o3.z * inv, o3.w * inv};
  ((float4*)op)[0] = r0; ((float4*)op)[1] = r1;
  ((float4*)op)[2] = r2; ((float4*)op)[3] = r3;
}

// ---------------- head: pool + concat + d1(LN) + d2(LN) + out ----------------
__global__ __launch_bounds__(128) void head(
    const float* __restrict__ X, const float* __restrict__ xo,
    const float* __restrict__ Wd1, const float* __restrict__ bd1,
    const float* __restrict__ s1, const float* __restrict__ b1,
    const float* __restrict__ Wd2, const float* __restrict__ bd2,
    const float* __restrict__ s2, const float* __restrict__ b2,
    const float* __restrict__ Wout, const float* __restrict__ bout,
    float* __restrict__ out) {
  __shared__ float c[D_ + FO];
  __shared__ float h1[128];
  __shared__ float sc[8];
  int b = blockIdx.x, tid = threadIdx.x;
  for (int cc = tid; cc < D_; cc += 128) {
    float acc = 0.f;
    for (int t = 0; t < S_; ++t) acc += X[((size_t)(b * S_ + t)) * D_ + cc];
    c[cc] = acc * (1.f / S_);
  }
  if (tid < FO) c[D_ + tid] = xo[b * FO + tid];
  __syncthreads();
  // dense1 (128 outputs) + relu + LN
  float v = bd1[tid];
  for (int k = 0; k < D_ + FO; ++k) v += c[k] * Wd1[k * 128 + tid];
  v = fmaxf(v, 0.f);
  float m = blk_sum(v, sc) * (1.f / 128.f);
  float d = v - m;
  float var = blk_sum(d * d, sc) * (1.f / 128.f);
  h1[tid] = d * rsqrtf(var + EPS) * s1[tid] + b1[tid];
  __syncthreads();
  // dense2 (64 outputs) + relu + LN
  float v2 = 0.f;
  if (tid < 64) {
    v2 = bd2[tid];
    for (int k = 0; k < 128; ++k) v2 += h1[k] * Wd2[k * 64 + tid];
    v2 = fmaxf(v2, 0.f);
  }
  float m2 = blk_sum(tid < 64 ? v2 : 0.f, sc) * (1.f / 64.f);
  float d2v = v2 - m2;
  float var2 = blk_sum(tid < 64 ? d2v * d2v : 0.f, sc) * (1.f / 64.f);
  float hv = (tid < 64) ? (d2v * rsqrtf(var2 + EPS) * s2[tid] + b2[tid]) : 0.f;
  float p = (tid < 64) ? hv * Wout[tid] : 0.f;
  float tot = blk_sum(p, sc);
  if (tid == 0) out[b] = tot + bout[0];
}

extern "C" void kernel_launch(void* const* d_in, const int* in_sizes, int n_in,
                              void* d_out, int out_size, void* d_ws,
                              size_t ws_size, hipStream_t stream) {
  const float* x_cgm = (const float*)d_in[0];
  const float* x_other = (const float*)d_in[1];
  const float* W_in = (const float*)d_in[2];
  const float* b_in = (const float*)d_in[3];
  const float* ln0_s = (const float*)d_in[4];
  const float* ln0_b = (const float*)d_in[5];
  const float* g0_Wg = (const float*)d_in[6];
  const float* g0_bg = (const float*)d_in[7];
  const float* g0_Wcx = (const float*)d_in[8];
  const float* g0_bcx = (const float*)d_in[9];
  const float* g0_Wch = (const float*)d_in[10];
  const float* g0_bch = (const float*)d_in[11];
  const float* g1_Wg = (const float*)d_in[12];
  const float* g1_bg = (const float*)d_in[13];
  const float* g1_Wcx = (const float*)d_in[14];
  const float* g1_bcx = (const float*)d_in[15];
  const float* g1_Wch = (const float*)d_in[16];
  const float* g1_bch = (const float*)d_in[17];
  const float* ln1_s = (const float*)d_in[18];
  const float* ln1_b = (const float*)d_in[19];
  const float* ln2_s = (const float*)d_in[20];
  const float* ln2_b = (const float*)d_in[21];
  const float* aln_s = (const float*)d_in[22];
  const float* aln_b = (const float*)d_in[23];
  const float* Wq = (const float*)d_in[24];
  const float* Wk = (const float*)d_in[25];
  const float* Wv = (const float*)d_in[26];
  const float* bq = (const float*)d_in[27];
  const float* bk = (const float*)d_in[28];
  const float* bv = (const float*)d_in[29];
  const float* Wo = (const float*)d_in[30];
  const float* bo = (const float*)d_in[31];
  const float* Wd1 = (const float*)d_in[32];
  const float* bd1 = (const float*)d_in[33];
  const float* lnd1_s = (const float*)d_in[34];
  const float* lnd1_b = (const float*)d_in[35];
  const float* Wd2 = (const float*)d_in[36];
  const float* bd2 = (const float*)d_in[37];
  const float* lnd2_s = (const float*)d_in[38];
  const float* lnd2_b = (const float*)d_in[39];
  const float* Wout = (const float*)d_in[40];
  const float* bout = (const float*)d_in[41];
  (void)in_sizes; (void)n_in; (void)out_size; (void)ws_size;

  float* ws = (float*)d_ws;
  float* X = ws;                // 4718592
  float* Yb = ws + NX;          // 4718592
  float* Gb = ws + 2 * NX;      // 9437184
  float* Cb = Gb + NG;          // 4718592
  float* Qb = Gb;               // qkv reuse G after GRU phases
  float* Kb = Gb + TOK * QKVN;
  float* Vb = Gb + 2 * TOK * QKVN;
  float* AO = Cb;

  const int MB = TOK / 128;     // 144

  inproj_ln<<<TOK, 256, 0, stream>>>(x_cgm, W_in, b_in, ln0_s, ln0_b, X);

  // GRU block 0
  gemm_mfma<128, 1, 0><<<dim3(MB, 4), 256, 0, stream>>>(X, g0_Wg, g0_bg, nullptr, Gb, 256, 512);
  gemm_mfma<128, 0, 0><<<dim3(MB, 2), 256, 0, stream>>>(X, g0_Wcx, g0_bcx, nullptr, Cb, 256, 256);
  gru_scan<<<B_, 1024, 0, stream>>>(Gb, Cb, g0_Wch, g0_bch, Yb);
  ln_token<1><<<TOK, 256, 0, stream>>>(Yb, ln1_s, ln1_b, X, X);

  // GRU block 1
  gemm_mfma<128, 1, 0><<<dim3(MB, 4), 256, 0, stream>>>(X, g1_Wg, g1_bg, nullptr, Gb, 256, 512);
  gemm_mfma<128, 0, 0><<<dim3(MB, 2), 256, 0, stream>>>(X, g1_Wcx, g1_bcx, nullptr, Cb, 256, 256);
  gru_scan<<<B_, 1024, 0, stream>>>(Gb, Cb, g1_Wch, g1_bch, Yb);
  ln_token<1><<<TOK, 256, 0, stream>>>(Yb, ln2_s, ln2_b, X, X);

  // attention
  ln_token<0><<<TOK, 256, 0, stream>>>(X, aln_s, aln_b, nullptr, Yb);
  gemm_mfma<64, 0, 0><<<dim3(MB, 1), 256, 0, stream>>>(Yb, Wq, bq, nullptr, Qb, 256, 64);
  gemm_mfma<64, 0, 0><<<dim3(MB, 1), 256, 0, stream>>>(Yb, Wk, bk, nullptr, Kb, 256, 64);
  gemm_mfma<64, 0, 0><<<dim3(MB, 1), 256, 0, stream>>>(Yb, Wv, bv, nullptr, Vb, 256, 64);
  attn<<<dim3(B_, 4), 320, 0, stream>>>(Qb, Kb, Vb, AO);
  gemm_mfma<128, 0, 1><<<dim3(MB, 2), 256, 0, stream>>>(AO, Wo, bo, X, X, 64, 256);

  // head
  head<<<B_, 128, 0, stream>>>(X, x_other, Wd1, bd1, lnd1_s, lnd1_b,
                               Wd2, bd2, lnd2_s, lnd2_b, Wout, bout,
                               (float*)d_out);
}

// Round 4
// 739.390 us; speedup vs baseline: 3.4743x; 1.2022x over previous
//
#include <hip/hip_runtime.h>
#include <hip/hip_bf16.h>
#include <math.h>

// GRUModel: B=64,S=288,Fc=16,Fo=32,D=256,QKV=64,HEADS=4,hd=16
// Round 4: gru_scan -> MFMA matvec. v broadcast-staged in LDS (512 B bf16);
// all 16 A-rows = copies of v, so output rows are replicated and the gate
// update runs redundantly in-register. Wch fragments preloaded to VGPRs once.
// GEMMs/LN/attn/head identical to round 3.
// ws layout (floats): X[18432*256] | Y[18432*256] | G[18432*512] | C[18432*256]

#define EPS 1e-5f
constexpr int B_ = 64, S_ = 288, FC = 16, FO = 32, D_ = 256, QKVN = 64, HD = 16;
constexpr int TOK = B_ * S_;            // 18432
constexpr int NX = TOK * D_;            // 4718592
constexpr int NG = TOK * 512;           // 9437184

typedef short bf16x8 __attribute__((ext_vector_type(8)));
typedef float f32x4 __attribute__((ext_vector_type(4)));

__device__ __forceinline__ short f2bf(float f) {
  __hip_bfloat16 h = __float2bfloat16(f);
  return __builtin_bit_cast(short, h);
}

// block-wide sum; blockDim multiple of 64, <=512. sc: >= blockDim/64 floats.
__device__ __forceinline__ float blk_sum(float v, float* sc) {
  #pragma unroll
  for (int o = 32; o > 0; o >>= 1) v += __shfl_down(v, o, 64);
  int tid = threadIdx.x;
  int wid = tid >> 6, nw = blockDim.x >> 6;
  __syncthreads();                      // protect sc from previous use
  if ((tid & 63) == 0) sc[wid] = v;
  __syncthreads();
  float s = 0.f;
  for (int w = 0; w < nw; ++w) s += sc[w];
  return s;
}

// ---------------- input projection + LN0: one block per token, 256 thr -------
__global__ __launch_bounds__(256) void inproj_ln(
    const float* __restrict__ xc, const float* __restrict__ Wi,
    const float* __restrict__ bi, const float* __restrict__ sc_,
    const float* __restrict__ bb, float* __restrict__ X) {
  __shared__ float sc[8];
  int tok = blockIdx.x, j = threadIdx.x;
  const float* xr = xc + tok * FC;
  float acc = bi[j];
  #pragma unroll
  for (int i = 0; i < FC; ++i) acc += xr[i] * Wi[i * D_ + j];
  float m = blk_sum(acc, sc) * (1.f / D_);
  float d = acc - m;
  float var = blk_sum(d * d, sc) * (1.f / D_);
  X[tok * D_ + j] = d * rsqrtf(var + EPS) * sc_[j] + bb[j];
}

// ---------------- LN over D=256 per token, optional residual add -------------
template <int RES>
__global__ __launch_bounds__(256) void ln_token(
    const float* __restrict__ in, const float* __restrict__ sc_,
    const float* __restrict__ bb, const float* __restrict__ resid,
    float* __restrict__ out) {
  __shared__ float sc[8];
  int tok = blockIdx.x, j = threadIdx.x;
  float v = in[tok * D_ + j];
  float m = blk_sum(v, sc) * (1.f / D_);
  float d = v - m;
  float var = blk_sum(d * d, sc) * (1.f / D_);
  float r = d * rsqrtf(var + EPS) * sc_[j] + bb[j];
  if (RES) r += resid[tok * D_ + j];
  out[tok * D_ + j] = r;
}

// ---------------- bf16 MFMA GEMM: OUT[M,N] = act(A@W + b)(+resid) -----------
// A fp32 [M,K] row-major, W fp32 [K,N] row-major; both cast to bf16 during LDS
// staging; fp32 accumulate. BM=128, BK=32, 256 thr (4 waves). Each wave owns a
// 32-row strip x BN cols = 2 x (BN/16) 16x16 C-tiles.
// grid = (M/128, N/BN). K in {256, 64}.
template <int BN, int ACT, int RES>
__global__ __launch_bounds__(256) void gemm_mfma(
    const float* __restrict__ A, const float* __restrict__ W,
    const float* __restrict__ bias, const float* __restrict__ resid,
    float* __restrict__ OUT, int K, int N) {
  constexpr int BM = 128, BK = 32;
  constexpr int NT16 = BN / 16;         // n-tiles per wave
  constexpr int BTASK = BN * 4 / 256;   // B staging tasks per thread
  __shared__ short As[BM * 40];
  __shared__ short Bs[BN * 40];
  int tid = threadIdx.x;
  int wave = tid >> 6, lane = tid & 63;
  int quad = lane >> 4, m16 = lane & 15;
  int row0 = blockIdx.x * BM;
  int bn0 = blockIdx.y * BN;

  f32x4 acc[2][NT16];
  #pragma unroll
  for (int mt = 0; mt < 2; ++mt)
    #pragma unroll
    for (int nt = 0; nt < NT16; ++nt) acc[mt][nt] = (f32x4){0.f, 0.f, 0.f, 0.f};

  const float* Ag = A + (size_t)row0 * K;

  for (int kk = 0; kk < K; kk += BK) {
    __syncthreads();                    // previous compute done before restage
    // ---- stage A tile 128x32: 1024 float4 tasks, 4/thread ----
    #pragma unroll
    for (int i = 0; i < 4; ++i) {
      int t = tid + i * 256;
      int r = t >> 3, kq = t & 7;       // row, k-quad (4 floats)
      float4 a4 = *(const float4*)(Ag + (size_t)r * K + kk + kq * 4);
      short4 s4 = make_short4(f2bf(a4.x), f2bf(a4.y), f2bf(a4.z), f2bf(a4.w));
      *(short4*)&As[r * 40 + kq * 4] = s4;
    }
    // ---- stage B tile 32xBN (n-major): BN*4 oct tasks ----
    #pragma unroll
    for (int i = 0; i < BTASK; ++i) {
      int t = tid + i * 256;
      int n = t % BN, oct = t / BN;     // 8 consecutive k per task
      const float* bp = W + (size_t)(kk + oct * 8) * N + bn0 + n;
      bf16x8 bv;
      #pragma unroll
      for (int j = 0; j < 8; ++j) bv[j] = f2bf(bp[(size_t)j * N]);
      *(bf16x8*)&Bs[n * 40 + oct * 8] = bv;
    }
    __syncthreads();
    // ---- MFMA: A[m=lane&15][k=quad*8+j], B[k=quad*8+j][n=lane&15] ----
    bf16x8 af0 = *(const bf16x8*)&As[(wave * 32 + m16) * 40 + quad * 8];
    bf16x8 af1 = *(const bf16x8*)&As[(wave * 32 + 16 + m16) * 40 + quad * 8];
    #pragma unroll
    for (int nt = 0; nt < NT16; ++nt) {
      bf16x8 bfr = *(const bf16x8*)&Bs[(nt * 16 + m16) * 40 + quad * 8];
      acc[0][nt] = __builtin_amdgcn_mfma_f32_16x16x32_bf16(af0, bfr, acc[0][nt], 0, 0, 0);
      acc[1][nt] = __builtin_amdgcn_mfma_f32_16x16x32_bf16(af1, bfr, acc[1][nt], 0, 0, 0);
    }
  }
  // ---- epilogue: C/D layout col=lane&15, row=quad*4+reg ----
  #pragma unroll
  for (int mt = 0; mt < 2; ++mt) {
    #pragma unroll
    for (int nt = 0; nt < NT16; ++nt) {
      int col = bn0 + nt * 16 + m16;
      float bv = bias[col];
      #pragma unroll
      for (int r = 0; r < 4; ++r) {
        int row = row0 + wave * 32 + mt * 16 + quad * 4 + r;
        float v = acc[mt][nt][r] + bv;
        if (ACT == 1) v = 1.f / (1.f + __expf(-v));
        if (RES) v += resid[(size_t)row * N + col];
        OUT[(size_t)row * N + col] = v;
      }
    }
  }
}

// ---------------- GRU sequential scan v3: 1 block/batch, 512 thr, MFMA ------
// v staged in LDS as bf16[256] (frag-linear == natural col order). Each quad
// reads the SAME 16B per chunk (broadcast ds_read_b128) -> all 16 A-rows are
// copies of v -> all C rows replicate the matvec result; h update runs
// redundantly in all lanes (bit-identical). Wch frags preloaded to VGPRs:
// wave w owns cols [32w,32w+32): 2 tiles x 8 chunks x 4 VGPR = 64 VGPR.
__global__ __launch_bounds__(512, 2) void gru_scan(
    const float* __restrict__ G, const float* __restrict__ C,
    const float* __restrict__ Wch, const float* __restrict__ bch,
    float* __restrict__ Y) {
  __shared__ short vstage[256];
  int tid = threadIdx.x;
  int b = blockIdx.x;
  int wave = tid >> 6, lane = tid & 63;
  int quad = lane >> 4, m16 = lane & 15;
  int col0 = 32 * wave + m16;           // tile 2w
  int col1 = col0 + 16;                 // tile 2w+1

  // one-time Wch fragment preload: B-frag[k=32c+quad*8+j][n=col]
  bf16x8 wfrag[2][8];
  #pragma unroll
  for (int tt = 0; tt < 2; ++tt) {
    int n = (tt == 0) ? col0 : col1;
    #pragma unroll
    for (int c = 0; c < 8; ++c) {
      const float* wp = Wch + (size_t)(32 * c + quad * 8) * D_ + n;
      bf16x8 w;
      #pragma unroll
      for (int j = 0; j < 8; ++j) w[j] = f2bf(wp[(size_t)j * D_]);
      wfrag[tt][c] = w;
    }
  }

  const float* Gp = G + (size_t)b * S_ * 512;
  const float* Cp = C + (size_t)b * S_ * 256;
  float* Yp = Y + (size_t)b * S_ * 256;

  float bch0 = bch[col0], bch1 = bch[col1];
  float h0 = 0.f, h1 = 0.f;
  float u0 = Gp[256 + col0], u1 = Gp[256 + col1];   // u_0
  float c0 = Cp[col0], c1 = Cp[col1];               // c_0
  float r0n = Gp[512 + col0], r1n = Gp[512 + col1]; // r_1

  if (tid < 256) vstage[tid] = 0;       // v_0 = r_0 * h_{-1} = 0
  __syncthreads();

  for (int t = 0; t < S_; ++t) {
    // matvec: A = broadcast v-frags, B = register W-frags
    f32x4 acc0 = {0.f, 0.f, 0.f, 0.f}, acc1 = {0.f, 0.f, 0.f, 0.f};
    #pragma unroll
    for (int c = 0; c < 8; ++c) {
      bf16x8 af = *(const bf16x8*)&vstage[(c * 4 + quad) * 8];
      acc0 = __builtin_amdgcn_mfma_f32_16x16x32_bf16(af, wfrag[0][c], acc0, 0, 0, 0);
      acc1 = __builtin_amdgcn_mfma_f32_16x16x32_bf16(af, wfrag[1][c], acc1, 0, 0, 0);
    }
    // prefetch next step's gate/candidate streams
    float u0n = 0.f, u1n = 0.f, c0n = 0.f, c1n = 0.f, r0nn = 0.f, r1nn = 0.f;
    if (t + 1 < S_) {
      size_t bn = (size_t)(t + 1);
      u0n = Gp[bn * 512 + 256 + col0]; u1n = Gp[bn * 512 + 256 + col1];
      c0n = Cp[bn * 256 + col0];       c1n = Cp[bn * 256 + col1];
    }
    if (t + 2 < S_) {
      size_t b2 = (size_t)(t + 2);
      r0nn = Gp[b2 * 512 + col0];      r1nn = Gp[b2 * 512 + col1];
    }
    // gate update (replicated across quads; deterministic)
    float s0 = c0 + bch0 + acc0[0];
    float s1 = c1 + bch1 + acc1[0];
    float e0 = __expf(2.f * s0), e1 = __expf(2.f * s1);
    float cand0 = 1.f - 2.f / (e0 + 1.f);
    float cand1 = 1.f - 2.f / (e1 + 1.f);
    h0 = u0 * h0 + (1.f - u0) * cand0;
    h1 = u1 * h1 + (1.f - u1) * cand1;
    short v0 = f2bf(r0n * h0), v1 = f2bf(r1n * h1);
    __syncthreads();                    // all v_t frag reads complete
    if (quad == 0) {
      Yp[(size_t)t * 256 + col0] = h0;
      Yp[(size_t)t * 256 + col1] = h1;
      vstage[col0] = v0;
      vstage[col1] = v1;
    }
    u0 = u0n; u1 = u1n; c0 = c0n; c1 = c1n; r0n = r0nn; r1n = r1nn;
    __syncthreads();                    // v_{t+1} visible to all waves
  }
}

// ---------------- flash attention: block=(b,head), 320 thr, K/V in LDS -------
__global__ __launch_bounds__(320) void attn(
    const float* __restrict__ Q, const float* __restrict__ Kv,
    const float* __restrict__ V, float* __restrict__ AO) {
  __shared__ float Kl[S_ * HD];
  __shared__ float Vl[S_ * HD];
  int b = blockIdx.x, hh = blockIdx.y;
  int tid = threadIdx.x;
  int hoff = hh * HD;
  for (int idx = tid; idx < S_ * HD; idx += 320) {
    int row = idx >> 4, d = idx & 15;
    Kl[idx] = Kv[((size_t)(b * S_ + row)) * QKVN + hoff + d];
    Vl[idx] = V[((size_t)(b * S_ + row)) * QKVN + hoff + d];
  }
  __syncthreads();
  if (tid >= S_) return;
  const float* qp = Q + ((size_t)(b * S_ + tid)) * QKVN + hoff;
  float4 q0 = *(const float4*)(qp + 0);
  float4 q1 = *(const float4*)(qp + 4);
  float4 q2 = *(const float4*)(qp + 8);
  float4 q3 = *(const float4*)(qp + 12);
  float m = -1e30f, l = 0.f;
  float4 o0 = {0, 0, 0, 0}, o1 = {0, 0, 0, 0}, o2 = {0, 0, 0, 0},
         o3 = {0, 0, 0, 0};
  for (int k = 0; k < S_; ++k) {
    const float4* kp = (const float4*)&Kl[k * HD];
    float4 k0 = kp[0], k1 = kp[1], k2 = kp[2], k3 = kp[3];
    float s = q0.x * k0.x + q0.y * k0.y + q0.z * k0.z + q0.w * k0.w +
              q1.x * k1.x + q1.y * k1.y + q1.z * k1.z + q1.w * k1.w +
              q2.x * k2.x + q2.y * k2.y + q2.z * k2.z + q2.w * k2.w +
              q3.x * k3.x + q3.y * k3.y + q3.z * k3.z + q3.w * k3.w;
    s *= 0.25f;                          // 1/sqrt(16)
    float mn = fmaxf(m, s);
    float corr = __expf(m - mn);
    float p = __expf(s - mn);
    l = l * corr + p;
    const float4* vp = (const float4*)&Vl[k * HD];
    float4 v0 = vp[0], v1 = vp[1], v2 = vp[2], v3 = vp[3];
    o0.x = o0.x * corr + p * v0.x; o0.y = o0.y * corr + p * v0.y;
    o0.z = o0.z * corr + p * v0.z; o0.w = o0.w * corr + p * v0.w;
    o1.x = o1.x * corr + p * v1.x; o1.y = o1.y * corr + p * v1.y;
    o1.z = o1.z * corr + p * v1.z; o1.w = o1.w * corr + p * v1.w;
    o2.x = o2.x * corr + p * v2.x; o2.y = o2.y * corr + p * v2.y;
    o2.z = o2.z * corr + p * v2.z; o2.w = o2.w * corr + p * v2.w;
    o3.x = o3.x * corr + p * v3.x; o3.y = o3.y * corr + p * v3.y;
    o3.z = o3.z * corr + p * v3.z; o3.w = o3.w * corr + p * v3.w;
    m = mn;
  }
  float inv = 1.f / l;
  float* op = AO + ((size_t)(b * S_ + tid)) * QKVN + hoff;
  float4 r0 = {o0.x * inv, o0.y * inv, o0.z * inv, o0.w * inv};
  float4 r1 = {o1.x * inv, o1.y * inv, o1.z * inv, o1.w * inv};
  float4 r2 = {o2.x * inv, o2.y * inv, o2.z * inv, o2.w * inv};
  float4 r3 = {o3.x * inv, o3.y * inv, o3.z * inv, o3.w * inv};
  ((float4*)op)[0] = r0; ((float4*)op)[1] = r1;
  ((float4*)op)[2] = r2; ((float4*)op)[3] = r3;
}

// ---------------- head: pool + concat + d1(LN) + d2(LN) + out ----------------
__global__ __launch_bounds__(128) void head(
    const float* __restrict__ X, const float* __restrict__ xo,
    const float* __restrict__ Wd1, const float* __restrict__ bd1,
    const float* __restrict__ s1, const float* __restrict__ b1,
    const float* __restrict__ Wd2, const float* __restrict__ bd2,
    const float* __restrict__ s2, const float* __restrict__ b2,
    const float* __restrict__ Wout, const float* __restrict__ bout,
    float* __restrict__ out) {
  __shared__ float c[D_ + FO];
  __shared__ float h1[128];
  __shared__ float sc[8];
  int b = blockIdx.x, tid = threadIdx.x;
  for (int cc = tid; cc < D_; cc += 128) {
    float acc = 0.f;
    for (int t = 0; t < S_; ++t) acc += X[((size_t)(b * S_ + t)) * D_ + cc];
    c[cc] = acc * (1.f / S_);
  }
  if (tid < FO) c[D_ + tid] = xo[b * FO + tid];
  __syncthreads();
  // dense1 (128 outputs) + relu + LN
  float v = bd1[tid];
  for (int k = 0; k < D_ + FO; ++k) v += c[k] * Wd1[k * 128 + tid];
  v = fmaxf(v, 0.f);
  float m = blk_sum(v, sc) * (1.f / 128.f);
  float d = v - m;
  float var = blk_sum(d * d, sc) * (1.f / 128.f);
  h1[tid] = d * rsqrtf(var + EPS) * s1[tid] + b1[tid];
  __syncthreads();
  // dense2 (64 outputs) + relu + LN
  float v2 = 0.f;
  if (tid < 64) {
    v2 = bd2[tid];
    for (int k = 0; k < 128; ++k) v2 += h1[k] * Wd2[k * 64 + tid];
    v2 = fmaxf(v2, 0.f);
  }
  float m2 = blk_sum(tid < 64 ? v2 : 0.f, sc) * (1.f / 64.f);
  float d2v = v2 - m2;
  float var2 = blk_sum(tid < 64 ? d2v * d2v : 0.f, sc) * (1.f / 64.f);
  float hv = (tid < 64) ? (d2v * rsqrtf(var2 + EPS) * s2[tid] + b2[tid]) : 0.f;
  float p = (tid < 64) ? hv * Wout[tid] : 0.f;
  float tot = blk_sum(p, sc);
  if (tid == 0) out[b] = tot + bout[0];
}

extern "C" void kernel_launch(void* const* d_in, const int* in_sizes, int n_in,
                              void* d_out, int out_size, void* d_ws,
                              size_t ws_size, hipStream_t stream) {
  const float* x_cgm = (const float*)d_in[0];
  const float* x_other = (const float*)d_in[1];
  const float* W_in = (const float*)d_in[2];
  const float* b_in = (const float*)d_in[3];
  const float* ln0_s = (const float*)d_in[4];
  const float* ln0_b = (const float*)d_in[5];
  const float* g0_Wg = (const float*)d_in[6];
  const float* g0_bg = (const float*)d_in[7];
  const float* g0_Wcx = (const float*)d_in[8];
  const float* g0_bcx = (const float*)d_in[9];
  const float* g0_Wch = (const float*)d_in[10];
  const float* g0_bch = (const float*)d_in[11];
  const float* g1_Wg = (const float*)d_in[12];
  const float* g1_bg = (const float*)d_in[13];
  const float* g1_Wcx = (const float*)d_in[14];
  const float* g1_bcx = (const float*)d_in[15];
  const float* g1_Wch = (const float*)d_in[16];
  const float* g1_bch = (const float*)d_in[17];
  const float* ln1_s = (const float*)d_in[18];
  const float* ln1_b = (const float*)d_in[19];
  const float* ln2_s = (const float*)d_in[20];
  const float* ln2_b = (const float*)d_in[21];
  const float* aln_s = (const float*)d_in[22];
  const float* aln_b = (const float*)d_in[23];
  const float* Wq = (const float*)d_in[24];
  const float* Wk = (const float*)d_in[25];
  const float* Wv = (const float*)d_in[26];
  const float* bq = (const float*)d_in[27];
  const float* bk = (const float*)d_in[28];
  const float* bv = (const float*)d_in[29];
  const float* Wo = (const float*)d_in[30];
  const float* bo = (const float*)d_in[31];
  const float* Wd1 = (const float*)d_in[32];
  const float* bd1 = (const float*)d_in[33];
  const float* lnd1_s = (const float*)d_in[34];
  const float* lnd1_b = (const float*)d_in[35];
  const float* Wd2 = (const float*)d_in[36];
  const float* bd2 = (const float*)d_in[37];
  const float* lnd2_s = (const float*)d_in[38];
  const float* lnd2_b = (const float*)d_in[39];
  const float* Wout = (const float*)d_in[40];
  const float* bout = (const float*)d_in[41];
  (void)in_sizes; (void)n_in; (void)out_size; (void)ws_size;

  float* ws = (float*)d_ws;
  float* X = ws;                // 4718592
  float* Yb = ws + NX;          // 4718592
  float* Gb = ws + 2 * NX;      // 9437184
  float* Cb = Gb + NG;          // 4718592
  float* Qb = Gb;               // qkv reuse G after GRU phases
  float* Kb = Gb + TOK * QKVN;
  float* Vb = Gb + 2 * TOK * QKVN;
  float* AO = Cb;

  const int MB = TOK / 128;     // 144

  inproj_ln<<<TOK, 256, 0, stream>>>(x_cgm, W_in, b_in, ln0_s, ln0_b, X);

  // GRU block 0
  gemm_mfma<128, 1, 0><<<dim3(MB, 4), 256, 0, stream>>>(X, g0_Wg, g0_bg, nullptr, Gb, 256, 512);
  gemm_mfma<128, 0, 0><<<dim3(MB, 2), 256, 0, stream>>>(X, g0_Wcx, g0_bcx, nullptr, Cb, 256, 256);
  gru_scan<<<B_, 512, 0, stream>>>(Gb, Cb, g0_Wch, g0_bch, Yb);
  ln_token<1><<<TOK, 256, 0, stream>>>(Yb, ln1_s, ln1_b, X, X);

  // GRU block 1
  gemm_mfma<128, 1, 0><<<dim3(MB, 4), 256, 0, stream>>>(X, g1_Wg, g1_bg, nullptr, Gb, 256, 512);
  gemm_mfma<128, 0, 0><<<dim3(MB, 2), 256, 0, stream>>>(X, g1_Wcx, g1_bcx, nullptr, Cb, 256, 256);
  gru_scan<<<B_, 512, 0, stream>>>(Gb, Cb, g1_Wch, g1_bch, Yb);
  ln_token<1><<<TOK, 256, 0, stream>>>(Yb, ln2_s, ln2_b, X, X);

  // attention
  ln_token<0><<<TOK, 256, 0, stream>>>(X, aln_s, aln_b, nullptr, Yb);
  gemm_mfma<64, 0, 0><<<dim3(MB, 1), 256, 0, stream>>>(Yb, Wq, bq, nullptr, Qb, 256, 64);
  gemm_mfma<64, 0, 0><<<dim3(MB, 1), 256, 0, stream>>>(Yb, Wk, bk, nullptr, Kb, 256, 64);
  gemm_mfma<64, 0, 0><<<dim3(MB, 1), 256, 0, stream>>>(Yb, Wv, bv, nullptr, Vb, 256, 64);
  attn<<<dim3(B_, 4), 320, 0, stream>>>(Qb, Kb, Vb, AO);
  gemm_mfma<128, 0, 1><<<dim3(MB, 2), 256, 0, stream>>>(AO, Wo, bo, X, X, 64, 256);

  // head
  head<<<B_, 128, 0, stream>>>(X, x_other, Wd1, bd1, lnd1_s, lnd1_b,
                               Wd2, bd2, lnd2_s, lnd2_b, Wout, bout,
                               (float*)d_out);
}